// Round 6
// baseline (196.262 us; speedup 1.0000x reference)
//
#include <hip/hip_runtime.h>

// Problem constants (reference: BATCH=8192, IN_F=2048, OUT_F=2048)
#define M_DIM 8192
#define N_DIM 2048
#define K_DIM 2048
#define LN2F 0.69314718055994530942f
#define LOG2EF 1.44269504088896340736f
#define BIAS_PHI 0.62009741f  // softplus(1) - ln2 = log((1+e)/2)

// s_waitcnt immediates (gfx9 encoding): vmcnt[3:0]|[15:14], expcnt[6:4]=7
// (no wait), lgkmcnt[11:8]=15 (no wait).
#define WAIT_VM6 0x0F76  // vmcnt(6)
#define WAIT_VM0 0x0F70  // vmcnt(0)

typedef _Float16 f16x8 __attribute__((ext_vector_type(8)));
typedef float f32x4 __attribute__((ext_vector_type(4)));

// ---------------------------------------------------------------------------
// softplus(x) - ln2 via native v_exp_f32 (2^x) and v_log_f32 (log2):
//   t = x*log2e;  r = (log2(1 + 2^t) - 1) * ln2
// t >= 24: 2^t dominates -> r = x - ln2. t << 0: 2^t -> 0 -> r = -ln2 (ok).
// ---------------------------------------------------------------------------
__device__ __forceinline__ float softplus_m_ln2(float v) {
    float t = v * LOG2EF;
    float e = __builtin_amdgcn_exp2f(t);
    float r = (__builtin_amdgcn_logf(1.0f + e) - 1.0f) * LN2F;
    return t < 24.0f ? r : v - LN2F;
}

// ---------------------------------------------------------------------------
// Fused prep: blocks [0, 8192) do phi; blocks [8192, 10240) do W rows.
//   phi[b,i]  = f16(softplus(x[b,i]) - ln2)          (8 elems/thread, 16B st)
//   Wh[o,i]   = f16(W[o,i]) for i<2048 (N x K row-major)
//   bias[o]   = W[o,2048] * (softplus(1)-ln2)
// ---------------------------------------------------------------------------
__global__ __launch_bounds__(256) void prep_kernel(const float* __restrict__ x,
                                                   const float* __restrict__ W,
                                                   _Float16* __restrict__ phi,
                                                   _Float16* __restrict__ Wh,
                                                   float* __restrict__ bias) {
    if (blockIdx.x < 8192) {
        size_t i = ((size_t)blockIdx.x * blockDim.x + threadIdx.x) * 8;
        float4 v0 = *(const float4*)(x + i);
        float4 v1 = *(const float4*)(x + i + 4);
        union { _Float16 h[8]; uint4 u; } pk;
        pk.h[0] = (_Float16)softplus_m_ln2(v0.x);
        pk.h[1] = (_Float16)softplus_m_ln2(v0.y);
        pk.h[2] = (_Float16)softplus_m_ln2(v0.z);
        pk.h[3] = (_Float16)softplus_m_ln2(v0.w);
        pk.h[4] = (_Float16)softplus_m_ln2(v1.x);
        pk.h[5] = (_Float16)softplus_m_ln2(v1.y);
        pk.h[6] = (_Float16)softplus_m_ln2(v1.z);
        pk.h[7] = (_Float16)softplus_m_ln2(v1.w);
        *(uint4*)(phi + i) = pk.u;
    } else {
        const int o = blockIdx.x - 8192;
        const float* row = W + (size_t)o * (K_DIM + 1) + threadIdx.x * 8;
        union { _Float16 h[8]; uint4 u; } pk;
#pragma unroll
        for (int j = 0; j < 8; ++j)
            pk.h[j] = (_Float16)row[j];
        *(uint4*)(Wh + (size_t)o * K_DIM + threadIdx.x * 8) = pk.u;
        if (threadIdx.x == 0)
            bias[o] = W[(size_t)o * (K_DIM + 1) + K_DIM] * BIAS_PHI;
    }
}

// ---------------------------------------------------------------------------
// GEMM: C[m,n] = sum_k phi[m,k] * Wh[n,k] + bias[n]
//
// R6: true double-buffered K-loop. R5's model: ~53% of cycles were stalls
// from __syncthreads' forced vmcnt(0) drain (every wave eats full DMA
// latency every iter). Now tile k+1's DMA is issued into the other buffer
// BEFORE waiting on tile k, and the wait is s_waitcnt vmcnt(6) — exactly
// tile k's 6 per-wave loads — leaving k+1's 6 in flight (AITER's
// never-vmcnt(0) pattern). Raw s_barrier (no compiler drain):
//   barrier A: all waves done reading buf 1-p (their ds_reads completed —
//              compiler waits lgkmcnt before the MFMAs that consume them)
//   -> safe to overwrite buf 1-p with tile k+1's DMA
//   vmcnt(6); barrier B: every wave's tile-k loads landed -> safe to read.
//
// Geometry (unchanged from R5 except BK): block 256x128, BK=32, 4 waves in
// 2x2, wave tile 128x64 as 8x4 of 16x16x32 f16 MFMAs, acc[8][4].
// LDS = 2 x (16 KB A + 8 KB B) = 48 KB -> 2 blocks/CU. Grid 512 = 2/CU.
//
// XOR swizzle (BK=32 form, verified 0 conflicts in R2): row = 32 f16 = 4
// chunks of 16 B; physical chunk = logical ^ ((row>>1)&3). DMA keeps fixed
// lane->base+lane*16; lanes fetch the permuted global chunk (same 64 B
// segment -> coalescing unchanged). Reads apply the same XOR.
// ---------------------------------------------------------------------------
__global__ __launch_bounds__(256, 2) void kan_gemm(const _Float16* __restrict__ A,  // M x K
                                                   const _Float16* __restrict__ B,  // N x K
                                                   const float* __restrict__ bias,  // N
                                                   float* __restrict__ C) {         // M x N
    __shared__ __align__(16) _Float16 sA[2][256 * 32];  // 2 x 16 KB
    __shared__ __align__(16) _Float16 sB[2][128 * 32];  // 2 x 8 KB

    const int tid  = threadIdx.x;
    const int lane = tid & 63;
    const int wv   = tid >> 6;          // wave 0..3

    const size_t Arow0 = (size_t)blockIdx.x * 256;
    const size_t Brow0 = (size_t)blockIdx.y * 128;

    // Staging: one issue = 16 rows x 32 cols. Lane l -> row l>>2, physical
    // chunk l&3, fetches logical chunk (l&3)^((l>>3)&3).
    const int rS = lane >> 2;
    const int cS = ((lane & 3) ^ ((lane >> 3) & 3)) * 8;

    // A: wave wv stages rows [wv*64, wv*64+64) in 4 issues of 16 rows.
    const _Float16* gA = A + (Arow0 + wv * 64 + rS) * (size_t)K_DIM + cS;
    // B: wave wv stages rows [wv*32, wv*32+32) in 2 issues of 16 rows.
    const _Float16* gB = B + (Brow0 + wv * 32 + rS) * (size_t)K_DIM + cS;

    // wave position: 2x2 grid of 128x64 patches
    const int wr = (wv >> 1) * 128;
    const int wc = (wv & 1) * 64;
    // MFMA operand addressing: outer idx = lane&15, logical chunk lane>>4;
    // physical = logical ^ ((lr>>1)&3).
    const int lr  = lane & 15;
    const int kqs = ((lane >> 4) ^ ((lr >> 1) & 3)) * 8;

    f32x4 acc[8][4];
#pragma unroll
    for (int i = 0; i < 8; ++i)
#pragma unroll
        for (int j = 0; j < 4; ++j)
            acc[i][j] = (f32x4){0.0f, 0.0f, 0.0f, 0.0f};

    // stage tile (k0 elems) into buffer buf: 6 DMA issues per wave
    auto stage = [&](int k0, int buf) {
        const _Float16* ga = gA + k0;
        const _Float16* gb = gB + k0;
        _Float16* da = &sA[buf][wv * 64 * 32];
        _Float16* db = &sB[buf][wv * 32 * 32];
#pragma unroll
        for (int j = 0; j < 4; ++j)
            __builtin_amdgcn_global_load_lds(
                (const __attribute__((address_space(1))) void*)(ga + (size_t)j * 16 * K_DIM),
                (__attribute__((address_space(3))) void*)(da + j * 16 * 32), 16, 0, 0);
#pragma unroll
        for (int j = 0; j < 2; ++j)
            __builtin_amdgcn_global_load_lds(
                (const __attribute__((address_space(1))) void*)(gb + (size_t)j * 16 * K_DIM),
                (__attribute__((address_space(3))) void*)(db + j * 16 * 32), 16, 0, 0);
    };

    stage(0, 0);

    for (int k = 0; k < 64; ++k) {
        const int p = k & 1;
        // Barrier A: all waves finished reading buf 1-p (iter k-1's compute)
        __builtin_amdgcn_s_barrier();
        if (k < 63) {
            stage((k + 1) * 32, 1 - p);
            __builtin_amdgcn_s_waitcnt(WAIT_VM6);  // tile k done, k+1 in flight
        } else {
            __builtin_amdgcn_s_waitcnt(WAIT_VM0);  // last tile: drain
        }
        // Barrier B: every wave's tile-k DMA has landed
        __builtin_amdgcn_s_barrier();

        const _Float16* sAp = sA[p];
        const _Float16* sBp = sB[p];
        f16x8 bfr[4];
#pragma unroll
        for (int ni = 0; ni < 4; ++ni)
            bfr[ni] = *(const f16x8*)&sBp[(wc + ni * 16 + lr) * 32 + kqs];

#pragma unroll
        for (int mh = 0; mh < 2; ++mh) {
            f16x8 af[4];
#pragma unroll
            for (int mi = 0; mi < 4; ++mi)
                af[mi] = *(const f16x8*)&sAp[(wr + (mh * 4 + mi) * 16 + lr) * 32 + kqs];
#pragma unroll
            for (int mi = 0; mi < 4; ++mi)
#pragma unroll
                for (int ni = 0; ni < 4; ++ni)
                    acc[mh * 4 + mi][ni] = __builtin_amdgcn_mfma_f32_16x16x32_f16(
                        af[mi], bfr[ni], acc[mh * 4 + mi][ni], 0, 0, 0);
        }
    }

    // Epilogue. C/D layout: col(n) = lane&15, row(m) = (lane>>4)*4 + reg.
    const int crow = (lane >> 4) * 4;
    float bsv[4];
#pragma unroll
    for (int ni = 0; ni < 4; ++ni)
        bsv[ni] = bias[Brow0 + wc + ni * 16 + lr];

#pragma unroll
    for (int mi = 0; mi < 8; ++mi) {
#pragma unroll
        for (int r = 0; r < 4; ++r) {
            float* cp = C + (Arow0 + wr + mi * 16 + crow + r) * (size_t)N_DIM
                        + Brow0 + wc + lr;
#pragma unroll
            for (int ni = 0; ni < 4; ++ni)
                cp[ni * 16] = acc[mi][ni][r] + bsv[ni];
        }
    }
}

// ---------------------------------------------------------------------------
extern "C" void kernel_launch(void* const* d_in, const int* in_sizes, int n_in,
                              void* d_out, int out_size, void* d_ws, size_t ws_size,
                              hipStream_t stream) {
    const float* x = (const float*)d_in[0];   // (8192, 2048) fp32
    const float* W = (const float*)d_in[1];   // (2048, 2049) fp32
    float* out = (float*)d_out;               // (8192, 2048) fp32

    // workspace layout: phi (M*K f16) | Wh (N*K f16) | bias (N f32)  ~42 MB
    char* ws = (char*)d_ws;
    _Float16* phi = (_Float16*)ws;
    _Float16* Wh  = (_Float16*)(ws + (size_t)M_DIM * K_DIM * sizeof(_Float16));
    float* bias   = (float*)(ws + (size_t)M_DIM * K_DIM * sizeof(_Float16)
                                + (size_t)N_DIM * K_DIM * sizeof(_Float16));

    prep_kernel<<<8192 + 2048, 256, 0, stream>>>(x, W, phi, Wh, bias);
    dim3 grid(M_DIM / 256, N_DIM / 128);  // 32 x 16 = 512 blocks, 2/CU
    kan_gemm<<<grid, 256, 0, stream>>>(phi, Wh, bias, out);
}